// Round 4
// baseline (400.534 us; speedup 1.0000x reference)
//
#include <hip/hip_runtime.h>

// MaxPool2d: kernel 2x2, stride 2x2, VALID padding, NCHW fp32.
// x: (16, 96, 224, 224) -> y: (16, 96, 112, 112)
// Streaming, zero reuse. Each thread produces a 2x2 output patch
// (2 output rows x 2 output cols):
//   - 4 independent dense fvec4 (dwordx4) nt loads, one per contributing
//     input row (2oh..2oh+3), 16 B/lane stride within each instruction
//   - 2 dense fvec2 (dwordx2) nt stores (output rows oh, oh+1)
// 4 loads in flight per thread doubles MLP vs the 2-load version.
// Row pitch 896 B = 14 x 64B lines, so wave row-straddle wastes no bytes.

typedef float fvec4 __attribute__((ext_vector_type(4)));
typedef float fvec2 __attribute__((ext_vector_type(2)));

#define N_  16
#define C_  96
#define H_  224
#define W_  224
#define OH_ 112
#define OW_ 112
#define PAIRS_PER_ROW (OW_ / 2)    // 56 column-pairs per output row
#define ROWPAIRS      (OH_ / 2)    // 56 row-pairs per image plane

__global__ __launch_bounds__(256) void maxpool2d_k(
    const float* __restrict__ x, float* __restrict__ y, int total) {
    int t = blockIdx.x * blockDim.x + threadIdx.x;
    if (t >= total) return;

    int p   = t % PAIRS_PER_ROW;   // column-pair index (output cols 2p, 2p+1)
    int rr  = t / PAIRS_PER_ROW;
    int oh2 = rr % ROWPAIRS;       // row-pair index (output rows 2*oh2, 2*oh2+1)
    int nc  = rr / ROWPAIRS;

    const fvec4* base = (const fvec4*)(x + ((size_t)nc * H_ + (size_t)(4 * oh2)) * W_) + p;
    const int rowq = W_ / 4;       // 56 float4s per input row

    fvec4 a0 = __builtin_nontemporal_load(base);
    fvec4 a1 = __builtin_nontemporal_load(base + rowq);
    fvec4 a2 = __builtin_nontemporal_load(base + 2 * rowq);
    fvec4 a3 = __builtin_nontemporal_load(base + 3 * rowq);

    fvec2 o0, o1;
    o0.x = fmaxf(fmaxf(a0.x, a0.y), fmaxf(a1.x, a1.y));
    o0.y = fmaxf(fmaxf(a0.z, a0.w), fmaxf(a1.z, a1.w));
    o1.x = fmaxf(fmaxf(a2.x, a2.y), fmaxf(a3.x, a3.y));
    o1.y = fmaxf(fmaxf(a2.z, a2.w), fmaxf(a3.z, a3.w));

    fvec2* dst = (fvec2*)(y + ((size_t)nc * OH_ + (size_t)(2 * oh2)) * OW_) + p;
    __builtin_nontemporal_store(o0, dst);
    __builtin_nontemporal_store(o1, dst + (OW_ / 2));
}

extern "C" void kernel_launch(void* const* d_in, const int* in_sizes, int n_in,
                              void* d_out, int out_size, void* d_ws, size_t ws_size,
                              hipStream_t stream) {
    const float* x = (const float*)d_in[0];
    float* y = (float*)d_out;

    const int total = N_ * C_ * ROWPAIRS * PAIRS_PER_ROW;  // 4,816,896
    const int block = 256;
    const int grid = (total + block - 1) / block;           // 18,816 blocks

    maxpool2d_k<<<grid, block, 0, stream>>>(x, y, total);
}